// Round 1
// baseline (1016.998 us; speedup 1.0000x reference)
//
#include <hip/hip_runtime.h>
#include <hip/hip_bf16.h>
#include <stdint.h>

// ---------------------------------------------------------------------------
// FluxSingleStreamBlock  B=1 L=2048 HID=3072 NH=24 HD=128 MLP=12288
// All GEMMs via mfma_f32_16x16x32_bf16 (m97-structure: global_load_lds w=16,
// 128x128 tile, BK=64, XOR-swizzled LDS). Weights converted fp32->bf16
// transposed [N][K] into a reused ws buffer. Flash attention, online softmax.
// ws requirement: ~227 MB.
// ---------------------------------------------------------------------------

typedef __bf16 bf16;
typedef bf16 bf16x2 __attribute__((ext_vector_type(2)));
typedef bf16 bf16x4 __attribute__((ext_vector_type(4)));
typedef bf16 bf16x8 __attribute__((ext_vector_type(8)));
typedef float f32x4 __attribute__((ext_vector_type(4)));

#define L_SEQ 2048
#define HIDD  3072
#define NHH   24
#define HDD   128
#define MLPD  12288
#define N3Q   9216

__device__ __forceinline__ void gload_lds16(const bf16* g, bf16* l) {
  __builtin_amdgcn_global_load_lds(
      (const __attribute__((address_space(1))) unsigned int*)g,
      (__attribute__((address_space(3))) unsigned int*)l, 16, 0, 0);
}

__device__ __forceinline__ float gelu_tanh(float x) {
  float z = 0.7978845608028654f * (x + 0.044715f * x * x * x);
  float t = 1.f - 2.f / (__expf(2.f * z) + 1.f);   // tanh(z), inf-safe
  return 0.5f * x * (1.f + t);
}

// ---------------- K1a: mod partial GEMV: silu(vec) @ w_mod ------------------
__global__ __launch_bounds__(256) void mod_partial(
    const float* __restrict__ vec, const float* __restrict__ w_mod,
    float* __restrict__ part) {
  __shared__ float sv[768];
  int y = blockIdx.y;
  int i0 = y * 768;
  for (int i = threadIdx.x; i < 768; i += 256) {
    float x = vec[i0 + i];
    sv[i] = x / (1.f + __expf(-x));
  }
  __syncthreads();
  int j = blockIdx.x * 256 + threadIdx.x;
  float acc = 0.f;
#pragma unroll 8
  for (int i = 0; i < 768; ++i)
    acc += sv[i] * w_mod[(size_t)(i0 + i) * N3Q + j];
  part[y * N3Q + j] = acc;
}

// ---------------- K1b: reduce partials + bias -> mod[9216] ------------------
__global__ __launch_bounds__(256) void mod_reduce(
    const float* __restrict__ part, const float* __restrict__ b_mod,
    float* __restrict__ mod) {
  int j = blockIdx.x * 256 + threadIdx.x;
  mod[j] = part[j] + part[N3Q + j] + part[2 * N3Q + j] + part[3 * N3Q + j] +
           b_mod[j];
}

// ---------------- K2: layernorm + modulate -> x_mod bf16 --------------------
__global__ __launch_bounds__(256) void ln_mod_k(
    const float* __restrict__ x, const float* __restrict__ mod,
    bf16* __restrict__ xm) {
  __shared__ float sb[4];
  int l = blockIdx.x, t = threadIdx.x;
  const float* xr = x + (size_t)l * HIDD;
  float4 v[3];
  float s = 0.f;
#pragma unroll
  for (int p = 0; p < 3; ++p) {
    v[p] = *(const float4*)(xr + p * 1024 + t * 4);
    s += v[p].x + v[p].y + v[p].z + v[p].w;
  }
#pragma unroll
  for (int o = 32; o >= 1; o >>= 1) s += __shfl_xor(s, o);
  if (!(t & 63)) sb[t >> 6] = s;
  __syncthreads();
  float mean = (sb[0] + sb[1] + sb[2] + sb[3]) * (1.f / HIDD);
  __syncthreads();
  float vs = 0.f;
#pragma unroll
  for (int p = 0; p < 3; ++p) {
    float a = v[p].x - mean, b = v[p].y - mean, c = v[p].z - mean,
          d = v[p].w - mean;
    vs += a * a + b * b + c * c + d * d;
  }
#pragma unroll
  for (int o = 32; o >= 1; o >>= 1) vs += __shfl_xor(vs, o);
  if (!(t & 63)) sb[t >> 6] = vs;
  __syncthreads();
  float var = (sb[0] + sb[1] + sb[2] + sb[3]) * (1.f / HIDD);
  float rs = rsqrtf(var + 1e-6f);
#pragma unroll
  for (int p = 0; p < 3; ++p) {
    int j = p * 1024 + t * 4;
    float4 sc = *(const float4*)(mod + HIDD + j);
    float4 sh = *(const float4*)(mod + j);
    bf16x4 o;
    o[0] = (bf16)((v[p].x - mean) * rs * (1.f + sc.x) + sh.x);
    o[1] = (bf16)((v[p].y - mean) * rs * (1.f + sc.y) + sh.y);
    o[2] = (bf16)((v[p].z - mean) * rs * (1.f + sc.z) + sh.z);
    o[3] = (bf16)((v[p].w - mean) * rs * (1.f + sc.w) + sh.w);
    *(bf16x4*)(xm + (size_t)l * HIDD + j) = o;
  }
}

// ---------------- convT: src [K][N] f32 -> dst [N][K] bf16 ------------------
__global__ __launch_bounds__(256) void convT(
    const float* __restrict__ src, bf16* __restrict__ dst, int K, int N) {
  __shared__ bf16 tl[64 * 72];
  int n0 = blockIdx.x * 64, k0 = blockIdx.y * 64;
  int t = threadIdx.x;
#pragma unroll
  for (int p = 0; p < 4; ++p) {
    int idx = p * 256 + t;
    int kr = idx >> 4, c4 = (idx & 15) << 2;
    float4 v = *(const float4*)(src + (size_t)(k0 + kr) * N + n0 + c4);
    bf16x4 b;
    b[0] = (bf16)v.x; b[1] = (bf16)v.y; b[2] = (bf16)v.z; b[3] = (bf16)v.w;
    *(bf16x4*)(tl + kr * 72 + c4) = b;
  }
  __syncthreads();
#pragma unroll
  for (int p = 0; p < 2; ++p) {
    int idx = p * 256 + t;
    int nr = idx >> 3, c = idx & 7;
    bf16x8 o;
#pragma unroll
    for (int j = 0; j < 8; ++j) o[j] = tl[(c * 8 + j) * 72 + nr];
    *(bf16x8*)(dst + (size_t)(n0 + nr) * K + k0 + c * 8) = o;
  }
}

// ---------------- GEMM: C[M,N] = A[M,K](bf16) * BT[N,K](bf16) + bias --------
// EPI: 0=QKV split, 1=GELU->mlp, 2=store f32 tmp, 3=final residual+gate
template <int EPI>
__global__ __launch_bounds__(256) void gemm_bt(
    const bf16* __restrict__ A, const bf16* __restrict__ BT,
    const float* __restrict__ bias, int M, int N, int K,
    float* __restrict__ e_f32a, const float* __restrict__ e_x,
    const float* __restrict__ e_mod, float* __restrict__ e_out,
    bf16* __restrict__ o0, bf16* __restrict__ o1, bf16* __restrict__ o2) {
  __shared__ bf16 As[128 * 64];
  __shared__ bf16 Bs[128 * 64];
  const int tid = threadIdx.x;
  const int lane = tid & 63, w = tid >> 6;
  const int wm = w >> 1, wn = w & 1;
  const int g = lane >> 4, r16 = lane & 15;
  const int row0 = blockIdx.x * 128, col0 = blockIdx.y * 128;

  f32x4 acc[4][4] = {};

  for (int k0 = 0; k0 < K; k0 += 64) {
    __syncthreads();
#pragma unroll
    for (int p = 0; p < 4; ++p) {
      int ci = p * 256 + tid;
      int rr = ci >> 3, cc = ci & 7;
      gload_lds16(A + (size_t)(row0 + rr) * K + k0 + ((cc ^ (rr & 7)) << 3),
                  As + ((p * 4 + w) << 9));
      gload_lds16(BT + (size_t)(col0 + rr) * K + k0 + ((cc ^ (rr & 7)) << 3),
                  Bs + ((p * 4 + w) << 9));
    }
    __syncthreads();
#pragma unroll
    for (int kk = 0; kk < 2; ++kk) {
      bf16x8 af[4], bff[4];
#pragma unroll
      for (int m = 0; m < 4; ++m) {
        int rr = wm * 64 + m * 16 + r16;
        af[m] = *(const bf16x8*)(As + rr * 64 + (((kk * 4 + g) ^ (rr & 7)) << 3));
      }
#pragma unroll
      for (int n = 0; n < 4; ++n) {
        int rr = wn * 64 + n * 16 + r16;
        bff[n] = *(const bf16x8*)(Bs + rr * 64 + (((kk * 4 + g) ^ (rr & 7)) << 3));
      }
#pragma unroll
      for (int m = 0; m < 4; ++m)
#pragma unroll
        for (int n = 0; n < 4; ++n)
          acc[m][n] = __builtin_amdgcn_mfma_f32_16x16x32_bf16(
              af[m], bff[n], acc[m][n], 0, 0, 0);
    }
  }

#pragma unroll
  for (int m = 0; m < 4; ++m) {
    int row = row0 + wm * 64 + m * 16 + g * 4;
#pragma unroll
    for (int n = 0; n < 4; ++n) {
      int col = col0 + wn * 64 + n * 16 + r16;
      float bv = bias[col];
#pragma unroll
      for (int r = 0; r < 4; ++r) {
        float v = acc[m][n][r] + bv;
        if (EPI == 0) {
          bf16* dst;
          int cl = col;
          if (col < 3072) { dst = o0; }
          else if (col < 6144) { dst = o1; cl -= 3072; }
          else { dst = o2; cl -= 6144; }
          dst[(size_t)(row + r) * HIDD + cl] = (bf16)v;
        } else if (EPI == 1) {
          o0[(size_t)(row + r) * MLPD + col] = (bf16)gelu_tanh(v);
        } else if (EPI == 2) {
          e_f32a[(size_t)(row + r) * HIDD + col] = v;
        } else {
          size_t idx = (size_t)(row + r) * HIDD + col;
          e_out[idx] = e_x[idx] + e_mod[6144 + col] * (e_f32a[idx] + v);
        }
      }
    }
  }
}

// ---------------- RMSNorm(Q,K) + RoPE (q scaled by 1/sqrt(128)) -------------
__global__ __launch_bounds__(256) void qknorm_rope_k(
    bf16* __restrict__ q, bf16* __restrict__ k, const float* __restrict__ pe,
    const float* __restrict__ qw, const float* __restrict__ kw) {
  int t = threadIdx.x, lane = t & 63, w = t >> 6;
  int pair = blockIdx.x * 4 + w;
  int h = pair % NHH, l = pair / NHH;
  size_t base = (size_t)l * HIDD + h * HDD + 2 * lane;
  float4 f = *(const float4*)(pe + (size_t)l * 256 + lane * 4);
  float2 wq = *(const float2*)(qw + 2 * lane);
  float2 wk = *(const float2*)(kw + 2 * lane);
  {
    bf16x2 xv = *(bf16x2*)(q + base);
    float x0 = (float)xv[0], x1 = (float)xv[1];
    float ss = x0 * x0 + x1 * x1;
#pragma unroll
    for (int o = 32; o >= 1; o >>= 1) ss += __shfl_xor(ss, o);
    float rs = rsqrtf(ss * (1.f / HDD) + 1.1920929e-7f);
    x0 *= rs * wq.x; x1 *= rs * wq.y;
    const float qs = 0.08838834764831845f;  // 1/sqrt(128)
    bf16x2 ov;
    ov[0] = (bf16)((f.x * x0 + f.y * x1) * qs);
    ov[1] = (bf16)((f.z * x0 + f.w * x1) * qs);
    *(bf16x2*)(q + base) = ov;
  }
  {
    bf16x2 xv = *(bf16x2*)(k + base);
    float x0 = (float)xv[0], x1 = (float)xv[1];
    float ss = x0 * x0 + x1 * x1;
#pragma unroll
    for (int o = 32; o >= 1; o >>= 1) ss += __shfl_xor(ss, o);
    float rs = rsqrtf(ss * (1.f / HDD) + 1.1920929e-7f);
    x0 *= rs * wk.x; x1 *= rs * wk.y;
    bf16x2 ov;
    ov[0] = (bf16)(f.x * x0 + f.y * x1);
    ov[1] = (bf16)(f.z * x0 + f.w * x1);
    *(bf16x2*)(k + base) = ov;
  }
}

// ---------------- V transpose: v[l][h*128+d] -> vt[h][d][l] -----------------
__global__ __launch_bounds__(256) void vtrans_k(
    const bf16* __restrict__ v, bf16* __restrict__ vt) {
  __shared__ bf16 tl[128 * 128];
  int t = threadIdx.x, lt = blockIdx.x, h = blockIdx.y;
#pragma unroll
  for (int p = 0; p < 8; ++p) {
    int idx = p * 256 + t;
    int i = idx >> 4, c = idx & 15;
    bf16x8 val =
        *(const bf16x8*)(v + (size_t)(lt * 128 + i) * HIDD + h * HDD + c * 8);
    *(bf16x8*)(tl + i * 128 + ((c ^ (i & 15)) << 3)) = val;
  }
  __syncthreads();
#pragma unroll
  for (int p = 0; p < 8; ++p) {
    int idx = p * 256 + t;
    int j = idx >> 4, i8 = (idx & 15) << 3;
    bf16x8 o;
#pragma unroll
    for (int e = 0; e < 8; ++e) {
      int row = i8 + e;
      o[e] = tl[row * 128 + ((((j >> 3) ^ (row & 15)) << 3) | (j & 7))];
    }
    *(bf16x8*)(vt + ((size_t)h * HDD + j) * L_SEQ + lt * 128 + i8) = o;
  }
}

// ---------------- Flash attention: 4 waves x 16 q-rows, KV tile 64 ----------
__global__ __launch_bounds__(256) void attn_k(
    const bf16* __restrict__ q, const bf16* __restrict__ k,
    const bf16* __restrict__ vt, bf16* __restrict__ out) {
  __shared__ bf16 Ks[64 * 128];   // [kv][d], chunk16 ^= kv&15
  __shared__ bf16 Vs[128 * 64];   // [d][kv], chunk8  ^= d&7
  __shared__ bf16 Ps[4][16 * 72]; // per-wave P [q][kv(64)+pad]
  int tid = threadIdx.x, lane = tid & 63, w = tid >> 6;
  int g = lane >> 4, r16 = lane & 15;
  int qt = blockIdx.x, h = blockIdx.y;
  int qbase = qt * 64 + w * 16;

  bf16x8 qreg[4];
  const bf16* qrow = q + (size_t)(qbase + r16) * HIDD + h * HDD;
#pragma unroll
  for (int c = 0; c < 4; ++c) qreg[c] = *(const bf16x8*)(qrow + c * 32 + g * 8);

  f32x4 acc[8] = {};
  float m_run = -3.0e38f, l_run = 0.f;
  bf16* ps = &Ps[w][0];

  for (int kv0 = 0; kv0 < L_SEQ; kv0 += 64) {
    __syncthreads();
#pragma unroll
    for (int p = 0; p < 4; ++p) {
      int ci = p * 256 + tid;
      {
        int rr = ci >> 4, cc = ci & 15;
        gload_lds16(k + (size_t)(kv0 + rr) * HIDD + h * HDD +
                        ((cc ^ (rr & 15)) << 3),
                    Ks + ((p * 4 + w) << 9));
      }
      {
        int rr = ci >> 3, cc = ci & 7;
        gload_lds16(vt + ((size_t)h * HDD + rr) * L_SEQ + kv0 +
                        ((cc ^ (rr & 7)) << 3),
                    Vs + ((p * 4 + w) << 9));
      }
    }
    __syncthreads();

    // S^T = K * Q^T  (rows kv, cols q)  -- scale folded into q
    f32x4 st[4] = {};
#pragma unroll
    for (int m4 = 0; m4 < 4; ++m4) {
#pragma unroll
      for (int c = 0; c < 4; ++c) {
        int rr = m4 * 16 + r16;
        bf16x8 kf =
            *(const bf16x8*)(Ks + rr * 128 + (((c * 4 + g) ^ (rr & 15)) << 3));
        st[m4] =
            __builtin_amdgcn_mfma_f32_16x16x32_bf16(kf, qreg[c], st[m4], 0, 0, 0);
      }
    }
    // online softmax (per q = r16, replicated across groups)
    float cmax = -3.0e38f;
#pragma unroll
    for (int m4 = 0; m4 < 4; ++m4)
#pragma unroll
      for (int r = 0; r < 4; ++r) cmax = fmaxf(cmax, st[m4][r]);
    cmax = fmaxf(cmax, __shfl_xor(cmax, 16));
    cmax = fmaxf(cmax, __shfl_xor(cmax, 32));
    float m_new = fmaxf(m_run, cmax);
    float corr = __expf(m_run - m_new);
    float psum = 0.f;
#pragma unroll
    for (int m4 = 0; m4 < 4; ++m4) {
      bf16x4 pk;
#pragma unroll
      for (int r = 0; r < 4; ++r) {
        float pv = __expf(st[m4][r] - m_new);
        psum += pv;
        pk[r] = (bf16)pv;
      }
      *(bf16x4*)(ps + r16 * 72 + m4 * 16 + g * 4) = pk;
    }
    psum += __shfl_xor(psum, 16);
    psum += __shfl_xor(psum, 32);
    l_run = l_run * corr + psum;
    m_run = m_new;
    float corr_r[4];
#pragma unroll
    for (int r = 0; r < 4; ++r) corr_r[r] = __shfl(corr, g * 4 + r);
#pragma unroll
    for (int nt = 0; nt < 8; ++nt)
#pragma unroll
      for (int r = 0; r < 4; ++r) acc[nt][r] *= corr_r[r];
    // PV
#pragma unroll
    for (int ks = 0; ks < 2; ++ks) {
      bf16x8 pf = *(const bf16x8*)(ps + r16 * 72 + ks * 32 + g * 8);
#pragma unroll
      for (int nt = 0; nt < 8; ++nt) {
        int rr = nt * 16 + r16;
        bf16x8 vf =
            *(const bf16x8*)(Vs + rr * 64 + (((ks * 4 + g) ^ (rr & 7)) << 3));
        acc[nt] = __builtin_amdgcn_mfma_f32_16x16x32_bf16(pf, vf, acc[nt], 0, 0, 0);
      }
    }
  }
  float inv = 1.f / l_run;
  float inv_r[4];
#pragma unroll
  for (int r = 0; r < 4; ++r) inv_r[r] = __shfl(inv, g * 4 + r);
#pragma unroll
  for (int nt = 0; nt < 8; ++nt)
#pragma unroll
    for (int r = 0; r < 4; ++r)
      out[(size_t)(qbase + g * 4 + r) * HIDD + h * HDD + nt * 16 + r16] =
          (bf16)(acc[nt][r] * inv_r[r]);
}

// ---------------------------------------------------------------------------
extern "C" void kernel_launch(void* const* d_in, const int* in_sizes, int n_in,
                              void* d_out, int out_size, void* d_ws,
                              size_t ws_size, hipStream_t stream) {
  const float* x     = (const float*)d_in[0];
  const float* vec   = (const float*)d_in[1];
  const float* pe    = (const float*)d_in[2];
  const float* w_mod = (const float*)d_in[3];
  const float* b_mod = (const float*)d_in[4];
  const float* w_qkv = (const float*)d_in[5];
  const float* b_qkv = (const float*)d_in[6];
  const float* w_fc1 = (const float*)d_in[7];
  const float* b_fc1 = (const float*)d_in[8];
  const float* w_fc2 = (const float*)d_in[9];
  const float* b_fc2 = (const float*)d_in[10];
  const float* w_out = (const float*)d_in[11];
  const float* b_out = (const float*)d_in[12];
  const float* qw    = (const float*)d_in[13];
  const float* kw    = (const float*)d_in[14];
  float* out = (float*)d_out;

  char* ws = (char*)d_ws;
  float* part = (float*)(ws + 0);            // 4*9216*4   = 147456
  float* mod  = (float*)(ws + 147456);       // 9216*4     = 36864
  bf16* xmod  = (bf16*)(ws + 184320);        // 12582912
  bf16* qb    = (bf16*)(ws + 12767232);      // 12582912
  bf16* kb    = (bf16*)(ws + 25350144);      // 12582912
  bf16* vb    = (bf16*)(ws + 37933056);      // 12582912
  bf16* vt    = (bf16*)(ws + 50515968);      // 12582912
  bf16* att   = (bf16*)(ws + 63098880);      // 12582912
  bf16* mlp   = (bf16*)(ws + 75681792);      // 50331648
  float* tmp  = (float*)(ws + 126013440);    // 25165824
  bf16* wt    = (bf16*)(ws + 151179264);     // 75497472 (reused, end 226676736)

  mod_partial<<<dim3(36, 4), 256, 0, stream>>>(vec, w_mod, part);
  mod_reduce<<<36, 256, 0, stream>>>(part, b_mod, mod);
  ln_mod_k<<<2048, 256, 0, stream>>>(x, mod, xmod);

  convT<<<dim3(144, 48), 256, 0, stream>>>(w_qkv, wt, 3072, 9216);
  gemm_bt<0><<<dim3(16, 72), 256, 0, stream>>>(xmod, wt, b_qkv, 2048, 9216,
                                               3072, nullptr, nullptr, nullptr,
                                               nullptr, qb, kb, vb);

  qknorm_rope_k<<<12288, 256, 0, stream>>>(qb, kb, pe, qw, kw);
  vtrans_k<<<dim3(16, 24), 256, 0, stream>>>(vb, vt);
  attn_k<<<dim3(32, 24), 256, 0, stream>>>(qb, kb, vt, att);

  convT<<<dim3(48, 48), 256, 0, stream>>>(w_out, wt, 3072, 3072);
  gemm_bt<2><<<dim3(16, 24), 256, 0, stream>>>(att, wt, b_out, 2048, 3072,
                                               3072, tmp, nullptr, nullptr,
                                               nullptr, nullptr, nullptr, nullptr);

  convT<<<dim3(192, 48), 256, 0, stream>>>(w_fc1, wt, 3072, 12288);
  gemm_bt<1><<<dim3(16, 96), 256, 0, stream>>>(xmod, wt, b_fc1, 2048, 12288,
                                               3072, nullptr, nullptr, nullptr,
                                               nullptr, mlp, nullptr, nullptr);

  convT<<<dim3(48, 192), 256, 0, stream>>>(w_fc2, wt, 12288, 3072);
  gemm_bt<3><<<dim3(16, 24), 256, 0, stream>>>(mlp, wt, b_fc2, 2048, 3072,
                                               12288, tmp, x, mod, out,
                                               nullptr, nullptr, nullptr);
}

// Round 2
// 925.410 us; speedup vs baseline: 1.0990x; 1.0990x over previous
//
#include <hip/hip_runtime.h>
#include <hip/hip_bf16.h>
#include <stdint.h>

// ---------------------------------------------------------------------------
// FluxSingleStreamBlock  B=1 L=2048 HID=3072 NH=24 HD=128 MLP=12288
// GEMMs: mfma_f32_16x16x32_bf16, 128x128 tile, BK=64, XOR-swizzled LDS,
// global_load_lds w=16, double-buffered issue-early prefetch (raw s_barrier +
// vmcnt(0), one barrier per K-step). fc2 split-K=2 into f32 partials reduced
// by a fused final kernel. Flash attention with online softmax.
// ---------------------------------------------------------------------------

typedef __bf16 bf16;
typedef bf16 bf16x2 __attribute__((ext_vector_type(2)));
typedef bf16 bf16x4 __attribute__((ext_vector_type(4)));
typedef bf16 bf16x8 __attribute__((ext_vector_type(8)));
typedef float f32x4 __attribute__((ext_vector_type(4)));

#define L_SEQ 2048
#define HIDD  3072
#define NHH   24
#define HDD   128
#define MLPD  12288
#define N3Q   9216

__device__ __forceinline__ void gload_lds16(const bf16* g, bf16* l) {
  __builtin_amdgcn_global_load_lds(
      (const __attribute__((address_space(1))) unsigned int*)g,
      (__attribute__((address_space(3))) unsigned int*)l, 16, 0, 0);
}

__device__ __forceinline__ float gelu_tanh(float x) {
  float z = 0.7978845608028654f * (x + 0.044715f * x * x * x);
  float t = 1.f - 2.f / (__expf(2.f * z) + 1.f);   // tanh(z), inf-safe
  return 0.5f * x * (1.f + t);
}

// ---------------- K1a: mod partial GEMV: silu(vec) @ w_mod ------------------
__global__ __launch_bounds__(256) void mod_partial(
    const float* __restrict__ vec, const float* __restrict__ w_mod,
    float* __restrict__ part) {
  __shared__ float sv[256];
  int y = blockIdx.y;
  int i0 = y * 256;
  {
    float xv = vec[i0 + threadIdx.x];
    sv[threadIdx.x] = xv / (1.f + __expf(-xv));
  }
  __syncthreads();
  int j = blockIdx.x * 256 + threadIdx.x;
  float acc = 0.f;
#pragma unroll 8
  for (int i = 0; i < 256; ++i)
    acc += sv[i] * w_mod[(size_t)(i0 + i) * N3Q + j];
  part[y * N3Q + j] = acc;
}

// ---------------- K1b: reduce partials + bias -> mod[9216] ------------------
__global__ __launch_bounds__(256) void mod_reduce(
    const float* __restrict__ part, const float* __restrict__ b_mod,
    float* __restrict__ mod) {
  int j = blockIdx.x * 256 + threadIdx.x;
  float s = b_mod[j];
#pragma unroll
  for (int p = 0; p < 12; ++p) s += part[p * N3Q + j];
  mod[j] = s;
}

// ---------------- K2: layernorm + modulate -> x_mod bf16 --------------------
__global__ __launch_bounds__(256) void ln_mod_k(
    const float* __restrict__ x, const float* __restrict__ mod,
    bf16* __restrict__ xm) {
  __shared__ float sb[4];
  int l = blockIdx.x, t = threadIdx.x;
  const float* xr = x + (size_t)l * HIDD;
  float4 v[3];
  float s = 0.f;
#pragma unroll
  for (int p = 0; p < 3; ++p) {
    v[p] = *(const float4*)(xr + p * 1024 + t * 4);
    s += v[p].x + v[p].y + v[p].z + v[p].w;
  }
#pragma unroll
  for (int o = 32; o >= 1; o >>= 1) s += __shfl_xor(s, o);
  if (!(t & 63)) sb[t >> 6] = s;
  __syncthreads();
  float mean = (sb[0] + sb[1] + sb[2] + sb[3]) * (1.f / HIDD);
  __syncthreads();
  float vs = 0.f;
#pragma unroll
  for (int p = 0; p < 3; ++p) {
    float a = v[p].x - mean, b = v[p].y - mean, c = v[p].z - mean,
          d = v[p].w - mean;
    vs += a * a + b * b + c * c + d * d;
  }
#pragma unroll
  for (int o = 32; o >= 1; o >>= 1) vs += __shfl_xor(vs, o);
  if (!(t & 63)) sb[t >> 6] = vs;
  __syncthreads();
  float var = (sb[0] + sb[1] + sb[2] + sb[3]) * (1.f / HIDD);
  float rs = rsqrtf(var + 1e-6f);
#pragma unroll
  for (int p = 0; p < 3; ++p) {
    int j = p * 1024 + t * 4;
    float4 sc = *(const float4*)(mod + HIDD + j);
    float4 sh = *(const float4*)(mod + j);
    bf16x4 o;
    o[0] = (bf16)((v[p].x - mean) * rs * (1.f + sc.x) + sh.x);
    o[1] = (bf16)((v[p].y - mean) * rs * (1.f + sc.y) + sh.y);
    o[2] = (bf16)((v[p].z - mean) * rs * (1.f + sc.z) + sh.z);
    o[3] = (bf16)((v[p].w - mean) * rs * (1.f + sc.w) + sh.w);
    *(bf16x4*)(xm + (size_t)l * HIDD + j) = o;
  }
}

// ---------------- convT: src [K][N] f32 -> dst [N][K] bf16 ------------------
__global__ __launch_bounds__(256) void convT(
    const float* __restrict__ src, bf16* __restrict__ dst, int K, int N) {
  __shared__ bf16 tl[64 * 72];
  int n0 = blockIdx.x * 64, k0 = blockIdx.y * 64;
  int t = threadIdx.x;
#pragma unroll
  for (int p = 0; p < 4; ++p) {
    int idx = p * 256 + t;
    int kr = idx >> 4, c4 = (idx & 15) << 2;
    float4 v = *(const float4*)(src + (size_t)(k0 + kr) * N + n0 + c4);
    bf16x4 b;
    b[0] = (bf16)v.x; b[1] = (bf16)v.y; b[2] = (bf16)v.z; b[3] = (bf16)v.w;
    *(bf16x4*)(tl + kr * 72 + c4) = b;
  }
  __syncthreads();
#pragma unroll
  for (int p = 0; p < 2; ++p) {
    int idx = p * 256 + t;
    int nr = idx >> 3, c = idx & 7;
    bf16x8 o;
#pragma unroll
    for (int j = 0; j < 8; ++j) o[j] = tl[(c * 8 + j) * 72 + nr];
    *(bf16x8*)(dst + (size_t)(n0 + nr) * K + k0 + c * 8) = o;
  }
}

// ---------------- GEMM: C[M,N] = A[M,k-range](bf16) * BT[N,k-range] ---------
// EPI: 0=QKV split, 1=GELU->mlp, 2=store f32 tmp (+bias), 4=split-K partial
template <int EPI>
__global__ __launch_bounds__(256) void gemm_bt(
    const bf16* __restrict__ A, const bf16* __restrict__ BT,
    const float* __restrict__ bias, int lda, int klen,
    float* __restrict__ e_p0, float* __restrict__ e_p1,
    bf16* __restrict__ o0, bf16* __restrict__ o1, bf16* __restrict__ o2) {
  __shared__ bf16 As[2][128 * 64];
  __shared__ bf16 Bs[2][128 * 64];
  const int tid = threadIdx.x;
  const int lane = tid & 63, w = tid >> 6;
  const int wm = w >> 1, wn = w & 1;
  const int g = lane >> 4, r16 = lane & 15;
  const int row0 = blockIdx.x * 128, col0 = blockIdx.y * 128;
  const int kb = (EPI == 4) ? blockIdx.z * klen : 0;

  // per-thread staging coordinates (pre-swizzled global source, linear LDS)
  const int s_rr = tid >> 3, s_cc = tid & 7;
  const bf16* gA = A + (size_t)(row0 + s_rr) * lda + kb + ((s_cc ^ (s_rr & 7)) << 3);
  const bf16* gB = BT + (size_t)(col0 + s_rr) * lda + kb + ((s_cc ^ (s_rr & 7)) << 3);

  f32x4 acc[4][4] = {};

#define STAGE(buf, koff)                                                      \
  {                                                                           \
    _Pragma("unroll") for (int p = 0; p < 4; ++p) {                           \
      gload_lds16(gA + (size_t)(p * 32) * lda + (koff),                       \
                  &As[buf][(p * 4 + w) << 9]);                                \
      gload_lds16(gB + (size_t)(p * 32) * lda + (koff),                       \
                  &Bs[buf][(p * 4 + w) << 9]);                                \
    }                                                                         \
  }

  const int nk = klen >> 6;
  STAGE(0, 0);
  asm volatile("s_waitcnt vmcnt(0)" ::: "memory");
  __builtin_amdgcn_s_barrier();
  __builtin_amdgcn_sched_barrier(0);

  int cur = 0;
  for (int it = 0; it < nk; ++it) {
    if (it + 1 < nk) STAGE(cur ^ 1, (it + 1) * 64);
    const bf16* as = As[cur];
    const bf16* bs = Bs[cur];
#pragma unroll
    for (int kk = 0; kk < 2; ++kk) {
      bf16x8 af[4], bff[4];
#pragma unroll
      for (int m = 0; m < 4; ++m) {
        int rr = wm * 64 + m * 16 + r16;
        af[m] = *(const bf16x8*)(as + rr * 64 + (((kk * 4 + g) ^ (rr & 7)) << 3));
      }
#pragma unroll
      for (int n = 0; n < 4; ++n) {
        int rr = wn * 64 + n * 16 + r16;
        bff[n] = *(const bf16x8*)(bs + rr * 64 + (((kk * 4 + g) ^ (rr & 7)) << 3));
      }
#pragma unroll
      for (int m = 0; m < 4; ++m)
#pragma unroll
        for (int n = 0; n < 4; ++n)
          acc[m][n] = __builtin_amdgcn_mfma_f32_16x16x32_bf16(
              af[m], bff[n], acc[m][n], 0, 0, 0);
    }
    __builtin_amdgcn_sched_barrier(0);
    asm volatile("s_waitcnt vmcnt(0)" ::: "memory");
    __builtin_amdgcn_s_barrier();
    __builtin_amdgcn_sched_barrier(0);
    cur ^= 1;
  }
#undef STAGE

  float* psel = (EPI == 4) ? (blockIdx.z ? e_p1 : e_p0) : e_p0;
#pragma unroll
  for (int m = 0; m < 4; ++m) {
    int row = row0 + wm * 64 + m * 16 + g * 4;
#pragma unroll
    for (int n = 0; n < 4; ++n) {
      int col = col0 + wn * 64 + n * 16 + r16;
      float bv = (EPI == 4) ? 0.f : bias[col];
#pragma unroll
      for (int r = 0; r < 4; ++r) {
        float v = acc[m][n][r] + bv;
        if (EPI == 0) {
          bf16* dst;
          int cl = col;
          if (col < 3072) { dst = o0; }
          else if (col < 6144) { dst = o1; cl -= 3072; }
          else { dst = o2; cl -= 6144; }
          dst[(size_t)(row + r) * HIDD + cl] = (bf16)v;
        } else if (EPI == 1) {
          o0[(size_t)(row + r) * MLPD + col] = (bf16)gelu_tanh(v);
        } else {
          psel[(size_t)(row + r) * HIDD + col] = v;
        }
      }
    }
  }
}

// ---------------- final: out = x + gate*(tmp + p0 + p1 + b_fc2) -------------
__global__ __launch_bounds__(256) void final_k(
    const float* __restrict__ x, const float* __restrict__ tmp,
    const float* __restrict__ p0, const float* __restrict__ p1,
    const float* __restrict__ mod, const float* __restrict__ b_fc2,
    float* __restrict__ out) {
  int l = blockIdx.x, t = threadIdx.x;
#pragma unroll
  for (int p = 0; p < 3; ++p) {
    int c = p * 1024 + t * 4;
    size_t idx = (size_t)l * HIDD + c;
    float4 xv = *(const float4*)(x + idx);
    float4 tv = *(const float4*)(tmp + idx);
    float4 a0 = *(const float4*)(p0 + idx);
    float4 a1 = *(const float4*)(p1 + idx);
    float4 gv = *(const float4*)(mod + 2 * HIDD + c);
    float4 bv = *(const float4*)(b_fc2 + c);
    float4 o;
    o.x = xv.x + gv.x * (tv.x + a0.x + a1.x + bv.x);
    o.y = xv.y + gv.y * (tv.y + a0.y + a1.y + bv.y);
    o.z = xv.z + gv.z * (tv.z + a0.z + a1.z + bv.z);
    o.w = xv.w + gv.w * (tv.w + a0.w + a1.w + bv.w);
    *(float4*)(out + idx) = o;
  }
}

// ---------------- RMSNorm(Q,K) + RoPE (q scaled by 1/sqrt(128)) -------------
__global__ __launch_bounds__(256) void qknorm_rope_k(
    bf16* __restrict__ q, bf16* __restrict__ k, const float* __restrict__ pe,
    const float* __restrict__ qw, const float* __restrict__ kw) {
  int t = threadIdx.x, lane = t & 63, w = t >> 6;
  int pair = blockIdx.x * 4 + w;
  int h = pair % NHH, l = pair / NHH;
  size_t base = (size_t)l * HIDD + h * HDD + 2 * lane;
  float4 f = *(const float4*)(pe + (size_t)l * 256 + lane * 4);
  float2 wq = *(const float2*)(qw + 2 * lane);
  float2 wk = *(const float2*)(kw + 2 * lane);
  {
    bf16x2 xv = *(bf16x2*)(q + base);
    float x0 = (float)xv[0], x1 = (float)xv[1];
    float ss = x0 * x0 + x1 * x1;
#pragma unroll
    for (int o = 32; o >= 1; o >>= 1) ss += __shfl_xor(ss, o);
    float rs = rsqrtf(ss * (1.f / HDD) + 1.1920929e-7f);
    x0 *= rs * wq.x; x1 *= rs * wq.y;
    const float qs = 0.08838834764831845f;  // 1/sqrt(128)
    bf16x2 ov;
    ov[0] = (bf16)((f.x * x0 + f.y * x1) * qs);
    ov[1] = (bf16)((f.z * x0 + f.w * x1) * qs);
    *(bf16x2*)(q + base) = ov;
  }
  {
    bf16x2 xv = *(bf16x2*)(k + base);
    float x0 = (float)xv[0], x1 = (float)xv[1];
    float ss = x0 * x0 + x1 * x1;
#pragma unroll
    for (int o = 32; o >= 1; o >>= 1) ss += __shfl_xor(ss, o);
    float rs = rsqrtf(ss * (1.f / HDD) + 1.1920929e-7f);
    x0 *= rs * wk.x; x1 *= rs * wk.y;
    bf16x2 ov;
    ov[0] = (bf16)(f.x * x0 + f.y * x1);
    ov[1] = (bf16)(f.z * x0 + f.w * x1);
    *(bf16x2*)(k + base) = ov;
  }
}

// ---------------- V transpose: v[l][h*128+d] -> vt[h][d][l] -----------------
__global__ __launch_bounds__(256) void vtrans_k(
    const bf16* __restrict__ v, bf16* __restrict__ vt) {
  __shared__ bf16 tl[128 * 128];
  int t = threadIdx.x, lt = blockIdx.x, h = blockIdx.y;
#pragma unroll
  for (int p = 0; p < 8; ++p) {
    int idx = p * 256 + t;
    int i = idx >> 4, c = idx & 15;
    bf16x8 val =
        *(const bf16x8*)(v + (size_t)(lt * 128 + i) * HIDD + h * HDD + c * 8);
    *(bf16x8*)(tl + i * 128 + ((c ^ (i & 15)) << 3)) = val;
  }
  __syncthreads();
#pragma unroll
  for (int p = 0; p < 8; ++p) {
    int idx = p * 256 + t;
    int j = idx >> 4, i8 = (idx & 15) << 3;
    bf16x8 o;
#pragma unroll
    for (int e = 0; e < 8; ++e) {
      int row = i8 + e;
      o[e] = tl[row * 128 + ((((j >> 3) ^ (row & 15)) << 3) | (j & 7))];
    }
    *(bf16x8*)(vt + ((size_t)h * HDD + j) * L_SEQ + lt * 128 + i8) = o;
  }
}

// ---------------- Flash attention: 4 waves x 16 q-rows, KV tile 64 ----------
__global__ __launch_bounds__(256) void attn_k(
    const bf16* __restrict__ q, const bf16* __restrict__ k,
    const bf16* __restrict__ vt, bf16* __restrict__ out) {
  __shared__ bf16 Ks[64 * 128];   // [kv][d], chunk16 ^= kv&15
  __shared__ bf16 Vs[128 * 64];   // [d][kv], chunk8  ^= d&7
  __shared__ bf16 Ps[4][16 * 72]; // per-wave P [q][kv(64)+pad]
  int tid = threadIdx.x, lane = tid & 63, w = tid >> 6;
  int g = lane >> 4, r16 = lane & 15;
  int qt = blockIdx.x, h = blockIdx.y;
  int qbase = qt * 64 + w * 16;

  bf16x8 qreg[4];
  const bf16* qrow = q + (size_t)(qbase + r16) * HIDD + h * HDD;
#pragma unroll
  for (int c = 0; c < 4; ++c) qreg[c] = *(const bf16x8*)(qrow + c * 32 + g * 8);

  f32x4 acc[8] = {};
  float m_run = -3.0e38f, l_run = 0.f;
  bf16* ps = &Ps[w][0];

  for (int kv0 = 0; kv0 < L_SEQ; kv0 += 64) {
    __syncthreads();
#pragma unroll
    for (int p = 0; p < 4; ++p) {
      int ci = p * 256 + tid;
      {
        int rr = ci >> 4, cc = ci & 15;
        gload_lds16(k + (size_t)(kv0 + rr) * HIDD + h * HDD +
                        ((cc ^ (rr & 15)) << 3),
                    Ks + ((p * 4 + w) << 9));
      }
      {
        int rr = ci >> 3, cc = ci & 7;
        gload_lds16(vt + ((size_t)h * HDD + rr) * L_SEQ + kv0 +
                        ((cc ^ (rr & 7)) << 3),
                    Vs + ((p * 4 + w) << 9));
      }
    }
    __syncthreads();

    // S^T = K * Q^T  (rows kv, cols q)  -- scale folded into q
    f32x4 st[4] = {};
#pragma unroll
    for (int m4 = 0; m4 < 4; ++m4) {
#pragma unroll
      for (int c = 0; c < 4; ++c) {
        int rr = m4 * 16 + r16;
        bf16x8 kf =
            *(const bf16x8*)(Ks + rr * 128 + (((c * 4 + g) ^ (rr & 15)) << 3));
        st[m4] =
            __builtin_amdgcn_mfma_f32_16x16x32_bf16(kf, qreg[c], st[m4], 0, 0, 0);
      }
    }
    // online softmax (per q = r16, replicated across groups)
    float cmax = -3.0e38f;
#pragma unroll
    for (int m4 = 0; m4 < 4; ++m4)
#pragma unroll
      for (int r = 0; r < 4; ++r) cmax = fmaxf(cmax, st[m4][r]);
    cmax = fmaxf(cmax, __shfl_xor(cmax, 16));
    cmax = fmaxf(cmax, __shfl_xor(cmax, 32));
    float m_new = fmaxf(m_run, cmax);
    float corr = __expf(m_run - m_new);
    float psum = 0.f;
#pragma unroll
    for (int m4 = 0; m4 < 4; ++m4) {
      bf16x4 pk;
#pragma unroll
      for (int r = 0; r < 4; ++r) {
        float pv = __expf(st[m4][r] - m_new);
        psum += pv;
        pk[r] = (bf16)pv;
      }
      *(bf16x4*)(ps + r16 * 72 + m4 * 16 + g * 4) = pk;
    }
    psum += __shfl_xor(psum, 16);
    psum += __shfl_xor(psum, 32);
    l_run = l_run * corr + psum;
    m_run = m_new;
    float corr_r[4];
#pragma unroll
    for (int r = 0; r < 4; ++r) corr_r[r] = __shfl(corr, g * 4 + r);
#pragma unroll
    for (int nt = 0; nt < 8; ++nt)
#pragma unroll
      for (int r = 0; r < 4; ++r) acc[nt][r] *= corr_r[r];
    // PV
#pragma unroll
    for (int ks = 0; ks < 2; ++ks) {
      bf16x8 pf = *(const bf16x8*)(ps + r16 * 72 + ks * 32 + g * 8);
#pragma unroll
      for (int nt = 0; nt < 8; ++nt) {
        int rr = nt * 16 + r16;
        bf16x8 vf =
            *(const bf16x8*)(Vs + rr * 64 + (((ks * 4 + g) ^ (rr & 7)) << 3));
        acc[nt] = __builtin_amdgcn_mfma_f32_16x16x32_bf16(pf, vf, acc[nt], 0, 0, 0);
      }
    }
  }
  float inv = 1.f / l_run;
  float inv_r[4];
#pragma unroll
  for (int r = 0; r < 4; ++r) inv_r[r] = __shfl(inv, g * 4 + r);
#pragma unroll
  for (int nt = 0; nt < 8; ++nt)
#pragma unroll
    for (int r = 0; r < 4; ++r)
      out[(size_t)(qbase + g * 4 + r) * HIDD + h * HDD + nt * 16 + r16] =
          (bf16)(acc[nt][r] * inv_r[r]);
}

// ---------------------------------------------------------------------------
extern "C" void kernel_launch(void* const* d_in, const int* in_sizes, int n_in,
                              void* d_out, int out_size, void* d_ws,
                              size_t ws_size, hipStream_t stream) {
  const float* x     = (const float*)d_in[0];
  const float* vec   = (const float*)d_in[1];
  const float* pe    = (const float*)d_in[2];
  const float* w_mod = (const float*)d_in[3];
  const float* b_mod = (const float*)d_in[4];
  const float* w_qkv = (const float*)d_in[5];
  const float* b_qkv = (const float*)d_in[6];
  const float* w_fc1 = (const float*)d_in[7];
  const float* b_fc1 = (const float*)d_in[8];
  const float* w_fc2 = (const float*)d_in[9];
  const float* b_fc2 = (const float*)d_in[10];
  const float* w_out = (const float*)d_in[11];
  const float* b_out = (const float*)d_in[12];
  const float* qw    = (const float*)d_in[13];
  const float* kw    = (const float*)d_in[14];
  float* out = (float*)d_out;

  char* ws = (char*)d_ws;
  float* mod  = (float*)(ws + 0);            //        36864
  bf16* xmod  = (bf16*)(ws + 36864);         //     12582912
  bf16* qb    = (bf16*)(ws + 12619776);
  bf16* kb    = (bf16*)(ws + 25202688);
  bf16* vb    = (bf16*)(ws + 37785600);
  bf16* vt    = (bf16*)(ws + 50368512);
  bf16* att   = (bf16*)(ws + 62951424);
  bf16* mlp   = (bf16*)(ws + 75534336);      //     50331648
  float* tmp  = (float*)(ws + 125865984);    //     25165824
  bf16* wt    = (bf16*)(ws + 151031808);     //     75497472 -> end 226529280
  float* part = (float*)(ws + 125865984);    // overlay on tmp (dead by then)
  float* pC   = (float*)(ws + 12619776);     // overlay qb+kb (dead after attn)
  float* pD   = (float*)(ws + 37785600);     // overlay vb+vt (dead after attn)

  mod_partial<<<dim3(36, 12), 256, 0, stream>>>(vec, w_mod, part);
  mod_reduce<<<36, 256, 0, stream>>>(part, b_mod, mod);
  ln_mod_k<<<2048, 256, 0, stream>>>(x, mod, xmod);

  convT<<<dim3(144, 48), 256, 0, stream>>>(w_qkv, wt, 3072, 9216);
  gemm_bt<0><<<dim3(16, 72), 256, 0, stream>>>(xmod, wt, b_qkv, 3072, 3072,
                                               nullptr, nullptr, qb, kb, vb);

  qknorm_rope_k<<<12288, 256, 0, stream>>>(qb, kb, pe, qw, kw);
  vtrans_k<<<dim3(16, 24), 256, 0, stream>>>(vb, vt);
  attn_k<<<dim3(32, 24), 256, 0, stream>>>(qb, kb, vt, att);

  convT<<<dim3(48, 48), 256, 0, stream>>>(w_out, wt, 3072, 3072);
  gemm_bt<2><<<dim3(16, 24), 256, 0, stream>>>(att, wt, b_out, 3072, 3072,
                                               tmp, nullptr, nullptr, nullptr,
                                               nullptr);

  convT<<<dim3(192, 48), 256, 0, stream>>>(w_fc1, wt, 3072, 12288);
  gemm_bt<1><<<dim3(16, 96), 256, 0, stream>>>(xmod, wt, b_fc1, 3072, 3072,
                                               nullptr, nullptr, mlp, nullptr,
                                               nullptr);

  convT<<<dim3(48, 192), 256, 0, stream>>>(w_fc2, wt, 12288, 3072);
  gemm_bt<4><<<dim3(16, 24, 2), 256, 0, stream>>>(mlp, wt, nullptr, 12288,
                                                  6144, pC, pD, nullptr,
                                                  nullptr, nullptr);
  final_k<<<2048, 256, 0, stream>>>(x, tmp, pC, pD, mod, b_fc2, out);
}